// Round 1
// baseline (1930.902 us; speedup 1.0000x reference)
//
#include <hip/hip_runtime.h>
#include <math.h>

#define NN 50000
#define NE 800000
#define INF 512
#define HID 64
#define OUTF 40
#define NL 16

// ---------------- setup kernels ----------------

__global__ __launch_bounds__(256) void k_deg(const int* __restrict__ src, const int* __restrict__ dst,
                                             int* __restrict__ dout, int* __restrict__ din) {
    int e = blockIdx.x * 256 + threadIdx.x;
    if (e < NE) {
        atomicAdd(&dout[src[e]], 1);
        atomicAdd(&din[dst[e]], 1);
    }
}

__global__ __launch_bounds__(256) void k_norm(const int* __restrict__ dout, const int* __restrict__ din,
                                              float* __restrict__ ns, float* __restrict__ nd) {
    int i = blockIdx.x * 256 + threadIdx.x;
    if (i < NN) {
        ns[i] = 1.0f / sqrtf((float)max(dout[i], 1));
        nd[i] = 1.0f / sqrtf((float)max(din[i], 1));
    }
}

// block-wise inclusive scan of deg_in
__global__ __launch_bounds__(256) void k_scanA(const int* __restrict__ din, int* __restrict__ incl,
                                               int* __restrict__ bsum) {
    __shared__ int lds[256];
    int i = blockIdx.x * 256 + threadIdx.x;
    int v = (i < NN) ? din[i] : 0;
    lds[threadIdx.x] = v;
    __syncthreads();
    for (int off = 1; off < 256; off <<= 1) {
        int t = (threadIdx.x >= off) ? lds[threadIdx.x - off] : 0;
        __syncthreads();
        lds[threadIdx.x] += t;
        __syncthreads();
    }
    if (i < NN) incl[i] = lds[threadIdx.x];
    if (threadIdx.x == 255) bsum[blockIdx.x] = lds[255];
}

// single-block scan of the 196 block sums -> exclusive offsets (in place)
__global__ __launch_bounds__(256) void k_scanB(int* __restrict__ bsum, int nb) {
    __shared__ int lds[256];
    int v = (threadIdx.x < nb) ? bsum[threadIdx.x] : 0;
    lds[threadIdx.x] = v;
    __syncthreads();
    for (int off = 1; off < 256; off <<= 1) {
        int t = (threadIdx.x >= off) ? lds[threadIdx.x - off] : 0;
        __syncthreads();
        lds[threadIdx.x] += t;
        __syncthreads();
    }
    if (threadIdx.x < nb) bsum[threadIdx.x] = lds[threadIdx.x] - v;  // exclusive
}

__global__ __launch_bounds__(256) void k_scanC(const int* __restrict__ incl, const int* __restrict__ din,
                                               const int* __restrict__ bsum, int* __restrict__ row_start,
                                               int* __restrict__ cursor) {
    int i = blockIdx.x * 256 + threadIdx.x;
    if (i < NN) {
        int rs = incl[i] - din[i] + bsum[i >> 8];
        row_start[i] = rs;
        cursor[i] = rs;
    }
}

__global__ __launch_bounds__(256) void k_fill(const int* __restrict__ src, const int* __restrict__ dst,
                                              int* __restrict__ cursor, int* __restrict__ col) {
    int e = blockIdx.x * 256 + threadIdx.x;
    if (e < NE) {
        int d = dst[e];
        int p = atomicAdd(&cursor[d], 1);
        col[p] = src[e];
    }
}

// premix weights: w1p = beta*W1 + (1-beta)*I, w2p likewise (folds residual terms into matmul)
__global__ __launch_bounds__(256) void k_wprep(const float* __restrict__ W1, const float* __restrict__ W2,
                                               float* __restrict__ w1p, float* __restrict__ w2p) {
    int i = blockIdx.x * 256 + threadIdx.x;  // over NL*HID*HID = 65536
    if (i < NL * HID * HID) {
        int l = i >> 12;
        int rc = i & 4095;
        int r = rc >> 6;
        int c = rc & 63;
        float beta = logf(0.5f / (float)(l + 1) + 1.0f);
        float d = (r == c) ? (1.0f - beta) : 0.0f;
        w1p[i] = beta * W1[i] + d;
        w2p[i] = beta * W2[i] + d;
    }
}

// ---------------- h0 = relu(feat @ W_in + b_in); also write hs = h0*norm_src, f0 = ALPHA*h0 ----------------
// lane = node; weights are wave-uniform -> scalar loads
__global__ __launch_bounds__(256) void k_gemm0(const float* __restrict__ feat, const float* __restrict__ Win,
                                               const float* __restrict__ bin, const float* __restrict__ ns,
                                               float* __restrict__ h, float* __restrict__ hs,
                                               float* __restrict__ f0) {
    int m = blockIdx.x * 256 + threadIdx.x;
    int mc = min(m, NN - 1);
    float acc[HID];
#pragma unroll
    for (int c = 0; c < HID; c++) acc[c] = 0.0f;
    const float4* frow = (const float4*)(feat + (size_t)mc * INF);
    for (int kc = 0; kc < INF / 4; ++kc) {
        float4 a = frow[kc];
        float av[4] = {a.x, a.y, a.z, a.w};
#pragma unroll
        for (int j = 0; j < 4; j++) {
            const float* wr = Win + (kc * 4 + j) * HID;
#pragma unroll
            for (int c = 0; c < HID; c++) acc[c] += av[j] * wr[c];
        }
    }
    if (m < NN) {
        float nsv = ns[m];
        float4* hp = (float4*)(h + (size_t)m * HID);
        float4* hsp = (float4*)(hs + (size_t)m * HID);
        float4* f0p = (float4*)(f0 + (size_t)m * HID);
#pragma unroll
        for (int c4 = 0; c4 < HID / 4; c4++) {
            float4 v;
            v.x = fmaxf(acc[c4 * 4 + 0] + bin[c4 * 4 + 0], 0.0f);
            v.y = fmaxf(acc[c4 * 4 + 1] + bin[c4 * 4 + 1], 0.0f);
            v.z = fmaxf(acc[c4 * 4 + 2] + bin[c4 * 4 + 2], 0.0f);
            v.w = fmaxf(acc[c4 * 4 + 3] + bin[c4 * 4 + 3], 0.0f);
            hp[c4] = v;
            float4 vs = {v.x * nsv, v.y * nsv, v.z * nsv, v.w * nsv};
            hsp[c4] = vs;
            float4 vf = {v.x * 0.1f, v.y * 0.1f, v.z * 0.1f, v.w * 0.1f};
            f0p[c4] = vf;
        }
    }
}

// ---------------- aggregation: f[n] = 0.9 * norm_dst[n] * sum_{e in CSR row n} hs[col[e]] ----------------
// one wave per node; lane = feature dim; coalesced 256B row gathers
__global__ __launch_bounds__(256) void k_agg(const float* __restrict__ hs, const int* __restrict__ col,
                                             const int* __restrict__ row_start, const int* __restrict__ din,
                                             const float* __restrict__ nd, float* __restrict__ f) {
    int n = (blockIdx.x * 256 + threadIdx.x) >> 6;  // 12500 blocks * 4 waves = 50000
    int lane = threadIdx.x & 63;
    int base = row_start[n];
    int deg = din[n];
    float acc = 0.0f;
    for (int done = 0; done < deg;) {
        int cnt = min(64, deg - done);
        int idxv = (lane < cnt) ? col[base + done + lane] : 0;
        int i = 0;
        for (; i + 4 <= cnt; i += 4) {
            int s0 = __shfl(idxv, i, 64);
            int s1 = __shfl(idxv, i + 1, 64);
            int s2 = __shfl(idxv, i + 2, 64);
            int s3 = __shfl(idxv, i + 3, 64);
            float v0 = hs[s0 * HID + lane];
            float v1 = hs[s1 * HID + lane];
            float v2 = hs[s2 * HID + lane];
            float v3 = hs[s3 * HID + lane];
            acc += (v0 + v1) + (v2 + v3);
        }
        for (; i < cnt; ++i) {
            int s = __shfl(idxv, i, 64);
            acc += hs[s * HID + lane];
        }
        done += cnt;
    }
    f[n * HID + lane] = 0.9f * nd[n] * acc;
}

// ---------------- layer matmul: h = relu(f@w1p + f0@w2p + bias); hs = h*norm_src ----------------
__global__ __launch_bounds__(256) void k_mm(const float* __restrict__ f, const float* __restrict__ f0,
                                            const float* __restrict__ w1p, const float* __restrict__ w2p,
                                            const float* __restrict__ bias, const float* __restrict__ ns,
                                            float* __restrict__ h, float* __restrict__ hs) {
    int m = blockIdx.x * 256 + threadIdx.x;
    int mc = min(m, NN - 1);
    float acc[HID];
#pragma unroll
    for (int c = 0; c < HID; c++) acc[c] = 0.0f;
    const float4* fr = (const float4*)(f + (size_t)mc * HID);
    for (int kc = 0; kc < HID / 4; ++kc) {
        float4 a = fr[kc];
        float av[4] = {a.x, a.y, a.z, a.w};
#pragma unroll
        for (int j = 0; j < 4; j++) {
            const float* wr = w1p + (kc * 4 + j) * HID;
#pragma unroll
            for (int c = 0; c < HID; c++) acc[c] += av[j] * wr[c];
        }
    }
    const float4* f0r = (const float4*)(f0 + (size_t)mc * HID);
    for (int kc = 0; kc < HID / 4; ++kc) {
        float4 a = f0r[kc];
        float av[4] = {a.x, a.y, a.z, a.w};
#pragma unroll
        for (int j = 0; j < 4; j++) {
            const float* wr = w2p + (kc * 4 + j) * HID;
#pragma unroll
            for (int c = 0; c < HID; c++) acc[c] += av[j] * wr[c];
        }
    }
    if (m < NN) {
        float nsv = ns[m];
        float4* hp = (float4*)(h + (size_t)m * HID);
        float4* hsp = (float4*)(hs + (size_t)m * HID);
#pragma unroll
        for (int c4 = 0; c4 < HID / 4; c4++) {
            float4 v;
            v.x = fmaxf(acc[c4 * 4 + 0] + bias[c4 * 4 + 0], 0.0f);
            v.y = fmaxf(acc[c4 * 4 + 1] + bias[c4 * 4 + 1], 0.0f);
            v.z = fmaxf(acc[c4 * 4 + 2] + bias[c4 * 4 + 2], 0.0f);
            v.w = fmaxf(acc[c4 * 4 + 3] + bias[c4 * 4 + 3], 0.0f);
            hp[c4] = v;
            float4 vs = {v.x * nsv, v.y * nsv, v.z * nsv, v.w * nsv};
            hsp[c4] = vs;
        }
    }
}

// ---------------- output: log_softmax(h @ W_out + b_out) ----------------
__global__ __launch_bounds__(256) void k_out(const float* __restrict__ h, const float* __restrict__ Wout,
                                             const float* __restrict__ bout, float* __restrict__ out) {
    int m = blockIdx.x * 256 + threadIdx.x;
    int mc = min(m, NN - 1);
    float acc[OUTF];
#pragma unroll
    for (int c = 0; c < OUTF; c++) acc[c] = 0.0f;
    const float4* hr = (const float4*)(h + (size_t)mc * HID);
    for (int kc = 0; kc < HID / 4; ++kc) {
        float4 a = hr[kc];
        float av[4] = {a.x, a.y, a.z, a.w};
#pragma unroll
        for (int j = 0; j < 4; j++) {
            const float* wr = Wout + (kc * 4 + j) * OUTF;
#pragma unroll
            for (int c = 0; c < OUTF; c++) acc[c] += av[j] * wr[c];
        }
    }
#pragma unroll
    for (int c = 0; c < OUTF; c++) acc[c] += bout[c];
    float mx = acc[0];
#pragma unroll
    for (int c = 1; c < OUTF; c++) mx = fmaxf(mx, acc[c]);
    float s = 0.0f;
#pragma unroll
    for (int c = 0; c < OUTF; c++) s += expf(acc[c] - mx);
    float lse = logf(s) + mx;
    if (m < NN) {
        float4* op = (float4*)(out + (size_t)m * OUTF);
#pragma unroll
        for (int c4 = 0; c4 < OUTF / 4; c4++) {
            float4 v;
            v.x = acc[c4 * 4 + 0] - lse;
            v.y = acc[c4 * 4 + 1] - lse;
            v.z = acc[c4 * 4 + 2] - lse;
            v.w = acc[c4 * 4 + 3] - lse;
            op[c4] = v;
        }
    }
}

extern "C" void kernel_launch(void* const* d_in, const int* in_sizes, int n_in,
                              void* d_out, int out_size, void* d_ws, size_t ws_size,
                              hipStream_t stream) {
    const float* feat = (const float*)d_in[0];
    const float* Win  = (const float*)d_in[1];
    const float* bin  = (const float*)d_in[2];
    const float* W1   = (const float*)d_in[3];
    const float* W2   = (const float*)d_in[4];
    const float* bvec = (const float*)d_in[5];
    const float* Wout = (const float*)d_in[6];
    const float* bout = (const float*)d_in[7];
    const int*   src  = (const int*)d_in[8];
    const int*   dst  = (const int*)d_in[9];
    float* out = (float*)d_out;

    char* ws = (char*)d_ws;
    size_t off = 0;
    auto take = [&](size_t bytes) {
        void* p = ws + off;
        off += (bytes + 255) & ~(size_t)255;
        return p;
    };
    int* deg_out   = (int*)take(NN * 4);
    int* deg_in    = (int*)take(NN * 4);
    int* incl      = (int*)take(NN * 4);
    int* bsum      = (int*)take(256 * 4);
    int* row_start = (int*)take(NN * 4);
    int* cursor    = (int*)take(NN * 4);
    int* col       = (int*)take(NE * 4);
    float* nsrc    = (float*)take(NN * 4);
    float* ndst    = (float*)take(NN * 4);
    float* w1p     = (float*)take((size_t)NL * HID * HID * 4);
    float* w2p     = (float*)take((size_t)NL * HID * HID * 4);
    float* f0      = (float*)take((size_t)NN * HID * 4);
    float* hbuf    = (float*)take((size_t)NN * HID * 4);
    float* hsbuf   = (float*)take((size_t)NN * HID * 4);
    float* fbuf    = (float*)take((size_t)NN * HID * 4);

    const int NB_N = (NN + 255) / 256;   // 196
    const int NB_E = (NE + 255) / 256;   // 3125

    hipMemsetAsync(deg_out, 0, NN * 4, stream);
    hipMemsetAsync(deg_in, 0, NN * 4, stream);

    k_deg<<<NB_E, 256, 0, stream>>>(src, dst, deg_out, deg_in);
    k_norm<<<NB_N, 256, 0, stream>>>(deg_out, deg_in, nsrc, ndst);
    k_scanA<<<NB_N, 256, 0, stream>>>(deg_in, incl, bsum);
    k_scanB<<<1, 256, 0, stream>>>(bsum, NB_N);
    k_scanC<<<NB_N, 256, 0, stream>>>(incl, deg_in, bsum, row_start, cursor);
    k_fill<<<NB_E, 256, 0, stream>>>(src, dst, cursor, col);
    k_wprep<<<(NL * HID * HID + 255) / 256, 256, 0, stream>>>(W1, W2, w1p, w2p);
    k_gemm0<<<NB_N, 256, 0, stream>>>(feat, Win, bin, nsrc, hbuf, hsbuf, f0);

    for (int l = 0; l < NL; ++l) {
        k_agg<<<NN / 4, 256, 0, stream>>>(hsbuf, col, row_start, deg_in, ndst, fbuf);
        k_mm<<<NB_N, 256, 0, stream>>>(fbuf, f0, w1p + l * HID * HID, w2p + l * HID * HID,
                                       bvec + l * HID, nsrc, hbuf, hsbuf);
    }
    k_out<<<NB_N, 256, 0, stream>>>(hbuf, Wout, bout, out);
}